// Round 16
// baseline (535.975 us; speedup 1.0000x reference)
//
#include <hip/hip_runtime.h>
#include <math.h>

#define NENT 40000
#define NTE  250000
#define NE   540000      // 2*NTE + NENT
#define DIM0 100
#define DIM  200
#define CCH  128
#define BQ   2048
#define FCK  25600       // CCH*DIM
#define EPSB 1e-5f
#define KPAD 224         // 200 padded to 7*32
#define EMBS 104         // emb16 row stride

typedef float f32x4 __attribute__((ext_vector_type(4)));
typedef _Float16 h8 __attribute__((ext_vector_type(8)));
typedef _Float16 h4 __attribute__((ext_vector_type(4)));

// =================== prep: zeroing + all input packing (one launch) ==========
// grid (2600, 6); section = blockIdx.y.
__global__ __launch_bounds__(256) void k_prep(
        const float* __restrict__ emb, const int* __restrict__ ent,
        const float* __restrict__ w2, const float* __restrict__ w3,
        const float* __restrict__ fcw,
        int* __restrict__ deg, float* __restrict__ fcsum,
        _Float16* __restrict__ emb16, _Float16* __restrict__ w2t,
        _Float16* __restrict__ w3t, _Float16* __restrict__ fcwf) {
    long i = (long)blockIdx.x * 256 + threadIdx.x;
    int sec = blockIdx.y;
    if (sec == 0) {
        if (i < NENT) deg[i] = 0;
    } else if (sec == 1) {
        if (i < BQ * DIM) fcsum[i] = 0.f;
    } else if (sec == 2) {
        if (i < (long)NENT * 13) {
            long m = i / 13;
            int k0 = (int)(i % 13) * 8;
            h8 h = {};
            const float* p = emb + (long)ent[m] * DIM0 + k0;
            #pragma unroll
            for (int j = 0; j < 8; j++)
                if (k0 + j < DIM0) h[j] = (_Float16)p[j];
            *(h8*)(emb16 + m * EMBS + k0) = h;
        }
    } else if (sec == 3) {
        if (i < 208 * 128) {
            int k = (int)(i % 128), n = (int)(i / 128);
            w2t[i] = (k < DIM0 && n < DIM) ? (_Float16)w2[(long)k * DIM + n] : (_Float16)0.f;
        }
    } else if (sec == 4) {
        if (i < 224 * KPAD) {
            int k = (int)(i % KPAD), n = (int)(i / KPAD);
            w3t[i] = (k < DIM && n < DIM) ? (_Float16)w3[(long)k * DIM + n] : (_Float16)0.f;
        }
    } else {
        if (i < (long)208 * (FCK / 8)) {
            int n = (int)(i / (FCK / 8));
            long k0 = (i % (FCK / 8)) * 8;
            h8 h = {};
            if (n < DIM) {
                const float* p = fcw + (long)n * FCK + k0;
                #pragma unroll
                for (int j = 0; j < 8; j++) h[j] = (_Float16)p[j];
            }
            *(h8*)(fcwf + (long)n * FCK + k0) = h;
        }
    }
}

// =================== CSR build ===================
__global__ void k_hist(const int* __restrict__ dst, int* __restrict__ deg) {
    int e = blockIdx.x * 256 + threadIdx.x;
    if (e < NE) atomicAdd(&deg[dst[e]], 1);
}

__global__ __launch_bounds__(1024) void k_scan(const int* __restrict__ deg,
        int* __restrict__ rowptr, int* __restrict__ cursor) {
    __shared__ int sums[1024];
    int t = threadIdx.x;
    int base = t * 40;
    int local[40];
    int s = 0;
    #pragma unroll
    for (int i = 0; i < 40; i++) {
        int idx = base + i;
        int v = (idx < NENT) ? deg[idx] : 0;
        local[i] = s;
        s += v;
    }
    sums[t] = s;
    __syncthreads();
    #pragma unroll
    for (int off = 1; off < 1024; off <<= 1) {
        int add = (t >= off) ? sums[t - off] : 0;
        __syncthreads();
        sums[t] += add;
        __syncthreads();
    }
    int prefix = (t == 0) ? 0 : sums[t - 1];
    #pragma unroll
    for (int i = 0; i < 40; i++) {
        int idx = base + i;
        if (idx < NENT) {
            int p = prefix + local[i];
            rowptr[idx] = p;
            cursor[idx] = p;
        }
    }
    if (t == 1023) rowptr[NENT] = prefix + s;
}

__global__ void k_scatter(const int* __restrict__ src, const int* __restrict__ dst,
                          const int* __restrict__ aet, const float* __restrict__ a2t,
                          const float* __restrict__ a3t, int* __restrict__ cursor,
                          int* __restrict__ ssrc, float* __restrict__ sa1,
                          float* __restrict__ sa2) {
    int e = blockIdx.x * 256 + threadIdx.x;
    if (e >= NE) return;
    int tt = (e < NTE) ? e + NTE : (e < 2 * NTE ? e - NTE : e);
    int t0 = aet[e], t1 = aet[tt];
    int pos = atomicAdd(&cursor[dst[e]], 1);
    ssrc[pos] = src[e];
    sa1[pos] = a2t[t0] + a2t[t1];
    sa2[pos] = a3t[t0] + a3t[t1];
}

// =================== raw CSR aggregation (pre-GEMM, linearity) ===============
template<int NL, int NPADL, int SS, int OS>
__global__ __launch_bounds__(256) void k_agg_raw(const int* __restrict__ rowptr,
        const int* __restrict__ ssrc, const float* __restrict__ sa,
        const _Float16* __restrict__ srcd, _Float16* __restrict__ outd) {
    int w = threadIdx.x >> 6, l = threadIdx.x & 63;
    int row = blockIdx.x * 4 + w;
    int beg = rowptr[row], end = rowptr[row + 1];
    bool act = l < NL;
    int col = l * 4;
    float sx = 0.f, sy = 0.f, sz = 0.f, sw = 0.f;
    int i = beg;
    for (; i + 4 <= end; i += 4) {
        int i0 = ssrc[i], i1 = ssrc[i + 1], i2 = ssrc[i + 2], i3 = ssrc[i + 3];
        float a0 = sa[i], a1 = sa[i + 1], a2 = sa[i + 2], a3 = sa[i + 3];
        if (act) {
            h4 v0 = *(const h4*)(srcd + (long)i0 * SS + col);
            h4 v1 = *(const h4*)(srcd + (long)i1 * SS + col);
            h4 v2 = *(const h4*)(srcd + (long)i2 * SS + col);
            h4 v3 = *(const h4*)(srcd + (long)i3 * SS + col);
            sx += a0 * (float)v0[0] + a1 * (float)v1[0] + a2 * (float)v2[0] + a3 * (float)v3[0];
            sy += a0 * (float)v0[1] + a1 * (float)v1[1] + a2 * (float)v2[1] + a3 * (float)v3[1];
            sz += a0 * (float)v0[2] + a1 * (float)v1[2] + a2 * (float)v2[2] + a3 * (float)v3[2];
            sw += a0 * (float)v0[3] + a1 * (float)v1[3] + a2 * (float)v2[3] + a3 * (float)v3[3];
        }
    }
    for (; i < end; i++) {
        int i0 = ssrc[i];
        float a0 = sa[i];
        if (act) {
            h4 v0 = *(const h4*)(srcd + (long)i0 * SS + col);
            sx += a0 * (float)v0[0]; sy += a0 * (float)v0[1];
            sz += a0 * (float)v0[2]; sw += a0 * (float)v0[3];
        }
    }
    if (act) {
        h4 o = { (_Float16)sx, (_Float16)sy, (_Float16)sz, (_Float16)sw };
        *(h4*)(outd + (long)row * OS + col) = o;
    } else if (l < NPADL) {
        h4 z = { (_Float16)0.f, (_Float16)0.f, (_Float16)0.f, (_Float16)0.f };
        *(h4*)(outd + (long)row * OS + col) = z;
    }
}

// decoder input: bn0-normalized [e(fp16 plane); rel_emb] -> hq16 fp16 [2048][400]
__global__ void k_hq16(const int* __restrict__ e1, const int* __restrict__ rel,
                       const _Float16* __restrict__ ef, const float* __restrict__ embrel,
                       const float* __restrict__ bn0, _Float16* __restrict__ hq) {
    int i = blockIdx.x * 256 + threadIdx.x;
    if (i >= BQ * 2 * DIM) return;
    int d = i % DIM, c = (i / DIM) & 1, b = i / (2 * DIM);
    float val = (c == 0) ? (float)ef[(long)e1[b] * KPAD + d]
                         : embrel[(long)rel[b] * DIM + d];
    float g = bn0[c], be = bn0[2 + c], m = bn0[4 + c], v = bn0[6 + c];
    hq[i] = (_Float16)(g * (val - m) * rsqrtf(v + EPSB) + be);
}

// ======= layer GEMM fused epilogue: C = tanh(bn(A@B + bias)) -> fp16 =========
template<int NT>
__global__ __launch_bounds__(256) void k_gemm16f(
        const _Float16* __restrict__ A, const _Float16* __restrict__ B,
        const float* __restrict__ bias, const float* __restrict__ bn,
        _Float16* __restrict__ C, int kpad, int ostride) {
    int w = threadIdx.x >> 6, l = threadIdx.x & 63;
    long m0 = (long)blockIdx.x * 64 + w * 16;
    long arow = m0 + (l & 15);
    int kg = (l >> 4) * 8;
    const _Float16* ap = A + arow * kpad + kg;
    f32x4 acc[NT];
    #pragma unroll
    for (int i = 0; i < NT; i++) acc[i] = (f32x4){0.f, 0.f, 0.f, 0.f};
    for (int kb = 0; kb < kpad; kb += 32) {
        h8 a = *(const h8*)(ap + kb);
        #pragma unroll
        for (int nt = 0; nt < NT; nt++) {
            h8 b = *(const h8*)(B + (long)(nt * 16 + (l & 15)) * kpad + kb + kg);
            acc[nt] = __builtin_amdgcn_mfma_f32_16x16x32_f16(a, b, acc[nt], 0, 0, 0);
        }
    }
    long rowo = m0 + (l >> 4) * 4;
    #pragma unroll
    for (int nt = 0; nt < NT; nt++) {
        int col = nt * 16 + (l & 15);
        if (col < ostride) {
            _Float16 vals[4];
            if (col < DIM) {
                float g = bn[col], be = bn[DIM + col], m = bn[2 * DIM + col],
                      v = bn[3 * DIM + col], bb = bias[col];
                float sc = g * rsqrtf(v + EPSB);
                #pragma unroll
                for (int rr = 0; rr < 4; rr++)
                    vals[rr] = (_Float16)tanhf(sc * (acc[nt][rr] + bb - m) + be);
            } else {
                #pragma unroll
                for (int rr = 0; rr < 4; rr++) vals[rr] = (_Float16)0.f;
            }
            #pragma unroll
            for (int rr = 0; rr < 4; rr++)
                C[(rowo + rr) * ostride + col] = vals[rr];
        }
    }
}

// =========== FUSED conv1d+bn1+relu + FC GEMM (split-K, atomics) ==============
__global__ __launch_bounds__(256) void k_convfc(
        const _Float16* __restrict__ hq16, const float* __restrict__ convw,
        const float* __restrict__ convb, const float* __restrict__ bn1,
        const _Float16* __restrict__ B, float* __restrict__ fcsum) {
    __shared__ _Float16 ldsA[64][40];
    __shared__ _Float16 ldsB[208][40];
    __shared__ float cwl[4][12];
    int bid = blockIdx.y * 8 + blockIdx.x;
    int wsw = (bid & 7) * 128 + (bid >> 3);
    int mb = wsw & 31, split = wsw >> 5;
    int t = threadIdx.x;
    int w = t >> 6, l = t & 63;
    int kbase = split * 800;
    int c0 = split * 4;
    if (t < 40) cwl[t / 10][t % 10] = convw[(c0 + t / 10) * 10 + t % 10];
    if (t < 4) {
        int c = c0 + t;
        float g = bn1[c], be = bn1[CCH + c], m = bn1[2 * CCH + c], v = bn1[3 * CCH + c];
        float s = g * rsqrtf(v + EPSB);
        cwl[t][10] = s;
        cwl[t][11] = be - m * s + s * convb[c];
    }
    __syncthreads();

    int r = t >> 2, q = t & 3;
    const _Float16* hrow = hq16 + (long)(mb * 64 + r) * 400;

    h8 z = {};
    h8 v0a, v1a, v2a, v0b, v1b, v2b;
    {
        int p = q * 8;
        v0a = (p >= 8) ? *(const h8*)(hrow + p - 8) : z;
        v1a = *(const h8*)(hrow + p);
        v2a = (p + 8 < DIM) ? *(const h8*)(hrow + p + 8) : z;
        v0b = (p >= 8) ? *(const h8*)(hrow + DIM + p - 8) : z;
        v1b = *(const h8*)(hrow + DIM + p);
        v2b = (p + 8 < DIM) ? *(const h8*)(hrow + DIM + p + 8) : z;
    }
    h8 bR[4];
    #pragma unroll
    for (int i2 = 0; i2 < 4; i2++) {
        int u = i2 * 256 + t;
        bR[i2] = (u < 832) ? *(const h8*)(B + (long)(u >> 2) * FCK + kbase + (u & 3) * 8) : z;
    }

    f32x4 acc[13];
    #pragma unroll
    for (int i = 0; i < 13; i++) acc[i] = (f32x4){0.f, 0.f, 0.f, 0.f};

    for (int ks = 0; ks < 25; ks++) {
        int off = ks * 32 + q * 8;
        int cl = off / 200;
        float cwv[12];
        #pragma unroll
        for (int k2 = 0; k2 < 12; k2++) cwv[k2] = cwl[cl][k2];
        float wa[12], wb[12];
        wa[0] = (float)v0a[6]; wa[1] = (float)v0a[7];
        wb[0] = (float)v0b[6]; wb[1] = (float)v0b[7];
        #pragma unroll
        for (int m2 = 0; m2 < 8; m2++) {
            wa[2 + m2] = (float)v1a[m2];
            wb[2 + m2] = (float)v1b[m2];
        }
        wa[10] = (float)v2a[0]; wa[11] = (float)v2a[1];
        wb[10] = (float)v2b[0]; wb[11] = (float)v2b[1];
        h8 aOut;
        #pragma unroll
        for (int j = 0; j < 8; j++) {
            float s = 0.f;
            #pragma unroll
            for (int kk = 0; kk < 5; kk++)
                s += wa[j + kk] * cwv[kk] + wb[j + kk] * cwv[5 + kk];
            aOut[j] = (_Float16)fmaxf(cwv[10] * s + cwv[11], 0.f);
        }
        *(h8*)&ldsA[r][q * 8] = aOut;
        #pragma unroll
        for (int i2 = 0; i2 < 4; i2++) {
            int u = i2 * 256 + t;
            if (u < 832) *(h8*)&ldsB[u >> 2][(u & 3) * 8] = bR[i2];
        }
        __syncthreads();
        if (ks + 1 < 25) {
            int off1 = (ks + 1) * 32 + q * 8;
            int cl1 = off1 / 200;
            int p1 = off1 - cl1 * 200;
            v0a = (p1 >= 8) ? *(const h8*)(hrow + p1 - 8) : z;
            v1a = *(const h8*)(hrow + p1);
            v2a = (p1 + 8 < DIM) ? *(const h8*)(hrow + p1 + 8) : z;
            v0b = (p1 >= 8) ? *(const h8*)(hrow + DIM + p1 - 8) : z;
            v1b = *(const h8*)(hrow + DIM + p1);
            v2b = (p1 + 8 < DIM) ? *(const h8*)(hrow + DIM + p1 + 8) : z;
            int knext = kbase + (ks + 1) * 32;
            #pragma unroll
            for (int i2 = 0; i2 < 4; i2++) {
                int u = i2 * 256 + t;
                if (u < 832) bR[i2] = *(const h8*)(B + (long)(u >> 2) * FCK + knext + (u & 3) * 8);
            }
        }
        h8 a = *(const h8*)&ldsA[w * 16 + (l & 15)][(l >> 4) * 8];
        #pragma unroll
        for (int nt = 0; nt < 13; nt++) {
            h8 b = *(const h8*)&ldsB[nt * 16 + (l & 15)][(l >> 4) * 8];
            acc[nt] = __builtin_amdgcn_mfma_f32_16x16x32_f16(a, b, acc[nt], 0, 0, 0);
        }
        __syncthreads();
    }
    long rowo = mb * 64 + w * 16 + (l >> 4) * 4;
    #pragma unroll
    for (int nt = 0; nt < 13; nt++) {
        int col = nt * 16 + (l & 15);
        if (col < DIM) {
            #pragma unroll
            for (int rr = 0; rr < 4; rr++)
                unsafeAtomicAdd(&fcsum[(rowo + rr) * DIM + col], acc[nt][rr]);
        }
    }
}

// =================== fcsum + bias + bn2 + relu -> h3 fp16 plane ===============
__global__ void k_fcreduce(const float* __restrict__ fcsum, const float* __restrict__ fcb,
                           const float* __restrict__ bn2, _Float16* __restrict__ h3) {
    int i = blockIdx.x * 256 + threadIdx.x;
    if (i >= BQ * KPAD) return;
    int j = i % KPAD, b = i / KPAD;
    _Float16 o = (_Float16)0.f;
    if (j < DIM) {
        float s = fcsum[(long)b * DIM + j] + fcb[j];
        float g = bn2[j], be = bn2[DIM + j], m = bn2[2 * DIM + j], v = bn2[3 * DIM + j];
        s = g * (s - m) * rsqrtf(v + EPSB) + be;
        o = (_Float16)fmaxf(s, 0.f);
    }
    h3[i] = o;
}

// =================== final: sigmoid(h3 @ e_all^T), fp16 MFMA =================
// grid (8, 1250); wave = 32 rows x 64 cols (acc[2][4], ~100 VGPR for higher
// occupancy); XCD swizzle: wsw=(bid%8)*1250+bid/8; mbb=wsw%16, nbb=wsw/16 ->
// B-tile reused 16x within one XCD's L2. A+B reg double-buffer; single-pass
// wave-local LDS transpose epilogue, full-line f32x4 NT stores.
__global__ __launch_bounds__(256) void k_mfma_final(
        const _Float16* __restrict__ A, const _Float16* __restrict__ B,
        float* __restrict__ out) {
    __shared__ float tl[4][32][68];
    int bid = blockIdx.y * 8 + blockIdx.x;
    int wsw = (bid & 7) * 1250 + (bid >> 3);
    int mbb = wsw & 15, nbb = wsw >> 4;
    int w = threadIdx.x >> 6, l = threadIdx.x & 63;
    int n0 = nbb * 64;
    int m0 = mbb * 128 + w * 32;
    int lr = l & 15;
    int kb = (l >> 4) * 8;
    const _Float16* aph = A + (long)(m0 + lr) * KPAD + kb;
    const _Float16* bph = B + (long)(n0 + lr) * KPAD + kb;
    h8 ac[2], bc[4], an[2], bn_[4];
    #pragma unroll
    for (int x = 0; x < 2; x++)
        ac[x] = *(const h8*)(aph + (long)x * 16 * KPAD);
    #pragma unroll
    for (int x = 0; x < 4; x++)
        bc[x] = *(const h8*)(bph + (long)x * 16 * KPAD);
    f32x4 acc[2][4];
    #pragma unroll
    for (int i = 0; i < 2; i++)
        #pragma unroll
        for (int j = 0; j < 4; j++) acc[i][j] = (f32x4){0.f, 0.f, 0.f, 0.f};
    for (int kt = 0; kt < 7; kt++) {
        int ko = kt * 32 + 32;
        if (kt < 6) {
            #pragma unroll
            for (int x = 0; x < 2; x++)
                an[x] = *(const h8*)(aph + (long)x * 16 * KPAD + ko);
            #pragma unroll
            for (int x = 0; x < 4; x++)
                bn_[x] = *(const h8*)(bph + (long)x * 16 * KPAD + ko);
        }
        #pragma unroll
        for (int mt = 0; mt < 2; mt++)
            #pragma unroll
            for (int nt = 0; nt < 4; nt++)
                acc[mt][nt] = __builtin_amdgcn_mfma_f32_16x16x32_f16(ac[mt], bc[nt], acc[mt][nt], 0, 0, 0);
        if (kt < 6) {
            #pragma unroll
            for (int x = 0; x < 2; x++) ac[x] = an[x];
            #pragma unroll
            for (int x = 0; x < 4; x++) bc[x] = bn_[x];
        }
    }
    #pragma unroll
    for (int mt = 0; mt < 2; mt++)
        #pragma unroll
        for (int nt = 0; nt < 4; nt++)
            #pragma unroll
            for (int r = 0; r < 4; r++)
                tl[w][mt * 16 + (l >> 4) * 4 + r][nt * 16 + lr] = acc[mt][nt][r];
    // wave-local LDS reuse: in-wave lgkmcnt ordering suffices (no barrier)
    #pragma unroll
    for (int i = 0; i < 8; i++) {
        int rr = i * 4 + (l >> 4);
        f32x4 v = *(const f32x4*)&tl[w][rr][lr * 4];
        f32x4 o;
        o.x = __builtin_amdgcn_rcpf(1.f + __expf(-v.x));
        o.y = __builtin_amdgcn_rcpf(1.f + __expf(-v.y));
        o.z = __builtin_amdgcn_rcpf(1.f + __expf(-v.z));
        o.w = __builtin_amdgcn_rcpf(1.f + __expf(-v.w));
        long row = m0 + rr;
        __builtin_nontemporal_store(o, (f32x4*)&out[row * NENT + n0 + lr * 4]);
    }
}

extern "C" void kernel_launch(void* const* d_in, const int* in_sizes, int n_in,
                              void* d_out, int out_size, void* d_ws, size_t ws_size,
                              hipStream_t stream) {
    (void)in_sizes; (void)n_in; (void)out_size; (void)ws_size;
    const int* src      = (const int*)d_in[0];
    const int* dst      = (const int*)d_in[1];
    const int* aet      = (const int*)d_in[2];
    const int* e1       = (const int*)d_in[3];
    const int* rel      = (const int*)d_in[4];
    const int* entity   = (const int*)d_in[5];
    const float* emb_e  = (const float*)d_in[6];
    const float* embrel = (const float*)d_in[7];
    const float* w2     = (const float*)d_in[8];
    const float* b2     = (const float*)d_in[9];
    const float* alpha2 = (const float*)d_in[10];
    const float* w3     = (const float*)d_in[11];
    const float* b3     = (const float*)d_in[12];
    const float* alpha3 = (const float*)d_in[13];
    const float* bn3    = (const float*)d_in[14];
    const float* bn4    = (const float*)d_in[15];
    const float* bn0    = (const float*)d_in[16];
    const float* bn1    = (const float*)d_in[17];
    const float* bn2    = (const float*)d_in[18];
    const float* convw  = (const float*)d_in[19];
    const float* convb  = (const float*)d_in[20];
    const float* fcw    = (const float*)d_in[21];
    const float* fcb    = (const float*)d_in[22];
    float* out = (float*)d_out;
    float* ws = (float*)d_ws;

    // ---- workspace layout (float offsets; non-overlapping) ----
    _Float16* emb16 = (_Float16*)ws;                 // [40000][104]
    _Float16* aggE  = (_Float16*)(ws + 3000000);     // [40000][128]
    _Float16* x1_f  = (_Float16*)(ws + 6000000);     // [40000][200]
    _Float16* aggX  = (_Float16*)(ws + 11000000);    // [40000][224]
    _Float16* e_f   = (_Float16*)(ws + 16000000);    // [40000][224]
    _Float16* fcw_f = (_Float16*)(ws + 21000000);    // [208][25600]
    _Float16* hq16  = (_Float16*)(ws + 24000000);    // [2048][400]
    int*   deg    = (int*)(ws + 51000000);
    int*   rowptr = (int*)(ws + 51050000);
    int*   cursor = (int*)(ws + 51100000);
    int*   ssrc   = (int*)(ws + 51200000);
    float* sa1    = ws + 51800000;
    float* sa2    = ws + 52400000;
    float* fcsum  = ws + 53000000;
    _Float16* h3_f  = (_Float16*)(ws + 54400000);    // [2048][224]
    _Float16* w2t_f = (_Float16*)(ws + 54700000);    // [208][128]
    _Float16* w3t_f = (_Float16*)(ws + 54750000);    // [224][224]

    // ---- prep: zero deg/fcsum + all packs (one launch) ----
    k_prep<<<dim3(2600, 6), 256, 0, stream>>>(emb_e, entity, w2, w3, fcw,
                                              deg, fcsum, emb16, w2t_f, w3t_f, fcw_f);

    // ---- CSR build (shared by both layers) ----
    k_hist<<<(NE + 255) / 256, 256, 0, stream>>>(dst, deg);
    k_scan<<<1, 1024, 0, stream>>>(deg, rowptr, cursor);
    k_scatter<<<(NE + 255) / 256, 256, 0, stream>>>(src, dst, aet, alpha2, alpha3,
                                                    cursor, ssrc, sa1, sa2);

    // ---- GCN layer 1: aggregate RAW emb (linearity), then GEMM+bn3+tanh ----
    k_agg_raw<26, 32, EMBS, 128><<<NENT / 4, 256, 0, stream>>>(rowptr, ssrc, sa1,
                                                               emb16, aggE);
    k_gemm16f<13><<<NENT / 64, 256, 0, stream>>>(aggE, w2t_f, b2, bn3, x1_f, 128, DIM);

    // ---- GCN layer 2: aggregate x1, then GEMM+bn4+tanh -> e plane ----
    k_agg_raw<50, 56, DIM, KPAD><<<NENT / 4, 256, 0, stream>>>(rowptr, ssrc, sa2,
                                                               x1_f, aggX);
    k_gemm16f<14><<<NENT / 64, 256, 0, stream>>>(aggX, w3t_f, b3, bn4, e_f, KPAD, KPAD);

    // ---- decoder input ----
    k_hq16<<<(BQ * 2 * DIM + 255) / 256, 256, 0, stream>>>(e1, rel, e_f, embrel, bn0, hq16);

    // ---- fused conv + FC (no hconv materialization) ----
    k_convfc<<<dim3(8, 128), 256, 0, stream>>>(hq16, convw, convb, bn1, fcw_f, fcsum);
    k_fcreduce<<<(BQ * KPAD + 255) / 256, 256, 0, stream>>>(fcsum, fcb, bn2, h3_f);

    // ---- final scoring ----
    k_mfma_final<<<dim3(8, 1250), 256, 0, stream>>>(h3_f, e_f, out);
}

// Round 17
// 505.050 us; speedup vs baseline: 1.0612x; 1.0612x over previous
//
#include <hip/hip_runtime.h>
#include <math.h>

#define NENT 40000
#define NTE  250000
#define NE   540000      // 2*NTE + NENT
#define DIM0 100
#define DIM  200
#define CCH  128
#define BQ   2048
#define FCK  25600       // CCH*DIM
#define EPSB 1e-5f
#define KPAD 224         // 200 padded to 7*32
#define EMBS 104         // emb16 row stride

typedef float f32x4 __attribute__((ext_vector_type(4)));
typedef _Float16 h8 __attribute__((ext_vector_type(8)));
typedef _Float16 h4 __attribute__((ext_vector_type(4)));

// =================== prep: zeroing + all input packing (one launch) ==========
// grid (2600, 6); section = blockIdx.y.
__global__ __launch_bounds__(256) void k_prep(
        const float* __restrict__ emb, const int* __restrict__ ent,
        const float* __restrict__ w2, const float* __restrict__ w3,
        const float* __restrict__ fcw,
        int* __restrict__ deg, float* __restrict__ fcsum,
        _Float16* __restrict__ emb16, _Float16* __restrict__ w2t,
        _Float16* __restrict__ w3t, _Float16* __restrict__ fcwf) {
    long i = (long)blockIdx.x * 256 + threadIdx.x;
    int sec = blockIdx.y;
    if (sec == 0) {
        if (i < NENT) deg[i] = 0;
    } else if (sec == 1) {
        if (i < BQ * DIM) fcsum[i] = 0.f;
    } else if (sec == 2) {
        if (i < (long)NENT * 13) {
            long m = i / 13;
            int k0 = (int)(i % 13) * 8;
            h8 h = {};
            const float* p = emb + (long)ent[m] * DIM0 + k0;
            #pragma unroll
            for (int j = 0; j < 8; j++)
                if (k0 + j < DIM0) h[j] = (_Float16)p[j];
            *(h8*)(emb16 + m * EMBS + k0) = h;
        }
    } else if (sec == 3) {
        if (i < 208 * 128) {
            int k = (int)(i % 128), n = (int)(i / 128);
            w2t[i] = (k < DIM0 && n < DIM) ? (_Float16)w2[(long)k * DIM + n] : (_Float16)0.f;
        }
    } else if (sec == 4) {
        if (i < 224 * KPAD) {
            int k = (int)(i % KPAD), n = (int)(i / KPAD);
            w3t[i] = (k < DIM && n < DIM) ? (_Float16)w3[(long)k * DIM + n] : (_Float16)0.f;
        }
    } else {
        if (i < (long)208 * (FCK / 8)) {
            int n = (int)(i / (FCK / 8));
            long k0 = (i % (FCK / 8)) * 8;
            h8 h = {};
            if (n < DIM) {
                const float* p = fcw + (long)n * FCK + k0;
                #pragma unroll
                for (int j = 0; j < 8; j++) h[j] = (_Float16)p[j];
            }
            *(h8*)(fcwf + (long)n * FCK + k0) = h;
        }
    }
}

// =================== CSR build ===================
__global__ void k_hist(const int* __restrict__ dst, int* __restrict__ deg) {
    int e = blockIdx.x * 256 + threadIdx.x;
    if (e < NE) atomicAdd(&deg[dst[e]], 1);
}

__global__ __launch_bounds__(1024) void k_scan(const int* __restrict__ deg,
        int* __restrict__ rowptr, int* __restrict__ cursor) {
    __shared__ int sums[1024];
    int t = threadIdx.x;
    int base = t * 40;
    int local[40];
    int s = 0;
    #pragma unroll
    for (int i = 0; i < 40; i++) {
        int idx = base + i;
        int v = (idx < NENT) ? deg[idx] : 0;
        local[i] = s;
        s += v;
    }
    sums[t] = s;
    __syncthreads();
    #pragma unroll
    for (int off = 1; off < 1024; off <<= 1) {
        int add = (t >= off) ? sums[t - off] : 0;
        __syncthreads();
        sums[t] += add;
        __syncthreads();
    }
    int prefix = (t == 0) ? 0 : sums[t - 1];
    #pragma unroll
    for (int i = 0; i < 40; i++) {
        int idx = base + i;
        if (idx < NENT) {
            int p = prefix + local[i];
            rowptr[idx] = p;
            cursor[idx] = p;
        }
    }
    if (t == 1023) rowptr[NENT] = prefix + s;
}

__global__ void k_scatter(const int* __restrict__ src, const int* __restrict__ dst,
                          const int* __restrict__ aet, const float* __restrict__ a2t,
                          const float* __restrict__ a3t, int* __restrict__ cursor,
                          int* __restrict__ ssrc, float* __restrict__ sa1,
                          float* __restrict__ sa2) {
    int e = blockIdx.x * 256 + threadIdx.x;
    if (e >= NE) return;
    int tt = (e < NTE) ? e + NTE : (e < 2 * NTE ? e - NTE : e);
    int t0 = aet[e], t1 = aet[tt];
    int pos = atomicAdd(&cursor[dst[e]], 1);
    ssrc[pos] = src[e];
    sa1[pos] = a2t[t0] + a2t[t1];
    sa2[pos] = a3t[t0] + a3t[t1];
}

// =================== raw CSR aggregation (pre-GEMM, linearity) ===============
template<int NL, int NPADL, int SS, int OS>
__global__ __launch_bounds__(256) void k_agg_raw(const int* __restrict__ rowptr,
        const int* __restrict__ ssrc, const float* __restrict__ sa,
        const _Float16* __restrict__ srcd, _Float16* __restrict__ outd) {
    int w = threadIdx.x >> 6, l = threadIdx.x & 63;
    int row = blockIdx.x * 4 + w;
    int beg = rowptr[row], end = rowptr[row + 1];
    bool act = l < NL;
    int col = l * 4;
    float sx = 0.f, sy = 0.f, sz = 0.f, sw = 0.f;
    int i = beg;
    for (; i + 4 <= end; i += 4) {
        int i0 = ssrc[i], i1 = ssrc[i + 1], i2 = ssrc[i + 2], i3 = ssrc[i + 3];
        float a0 = sa[i], a1 = sa[i + 1], a2 = sa[i + 2], a3 = sa[i + 3];
        if (act) {
            h4 v0 = *(const h4*)(srcd + (long)i0 * SS + col);
            h4 v1 = *(const h4*)(srcd + (long)i1 * SS + col);
            h4 v2 = *(const h4*)(srcd + (long)i2 * SS + col);
            h4 v3 = *(const h4*)(srcd + (long)i3 * SS + col);
            sx += a0 * (float)v0[0] + a1 * (float)v1[0] + a2 * (float)v2[0] + a3 * (float)v3[0];
            sy += a0 * (float)v0[1] + a1 * (float)v1[1] + a2 * (float)v2[1] + a3 * (float)v3[1];
            sz += a0 * (float)v0[2] + a1 * (float)v1[2] + a2 * (float)v2[2] + a3 * (float)v3[2];
            sw += a0 * (float)v0[3] + a1 * (float)v1[3] + a2 * (float)v2[3] + a3 * (float)v3[3];
        }
    }
    for (; i < end; i++) {
        int i0 = ssrc[i];
        float a0 = sa[i];
        if (act) {
            h4 v0 = *(const h4*)(srcd + (long)i0 * SS + col);
            sx += a0 * (float)v0[0]; sy += a0 * (float)v0[1];
            sz += a0 * (float)v0[2]; sw += a0 * (float)v0[3];
        }
    }
    if (act) {
        h4 o = { (_Float16)sx, (_Float16)sy, (_Float16)sz, (_Float16)sw };
        *(h4*)(outd + (long)row * OS + col) = o;
    } else if (l < NPADL) {
        h4 z = { (_Float16)0.f, (_Float16)0.f, (_Float16)0.f, (_Float16)0.f };
        *(h4*)(outd + (long)row * OS + col) = z;
    }
}

// decoder input: bn0-normalized [e(fp16 plane); rel_emb] -> hq16 fp16 [2048][400]
__global__ void k_hq16(const int* __restrict__ e1, const int* __restrict__ rel,
                       const _Float16* __restrict__ ef, const float* __restrict__ embrel,
                       const float* __restrict__ bn0, _Float16* __restrict__ hq) {
    int i = blockIdx.x * 256 + threadIdx.x;
    if (i >= BQ * 2 * DIM) return;
    int d = i % DIM, c = (i / DIM) & 1, b = i / (2 * DIM);
    float val = (c == 0) ? (float)ef[(long)e1[b] * KPAD + d]
                         : embrel[(long)rel[b] * DIM + d];
    float g = bn0[c], be = bn0[2 + c], m = bn0[4 + c], v = bn0[6 + c];
    hq[i] = (_Float16)(g * (val - m) * rsqrtf(v + EPSB) + be);
}

// ======= layer GEMM fused epilogue: C = tanh(bn(A@B + bias)) -> fp16 =========
template<int NT>
__global__ __launch_bounds__(256) void k_gemm16f(
        const _Float16* __restrict__ A, const _Float16* __restrict__ B,
        const float* __restrict__ bias, const float* __restrict__ bn,
        _Float16* __restrict__ C, int kpad, int ostride) {
    int w = threadIdx.x >> 6, l = threadIdx.x & 63;
    long m0 = (long)blockIdx.x * 64 + w * 16;
    long arow = m0 + (l & 15);
    int kg = (l >> 4) * 8;
    const _Float16* ap = A + arow * kpad + kg;
    f32x4 acc[NT];
    #pragma unroll
    for (int i = 0; i < NT; i++) acc[i] = (f32x4){0.f, 0.f, 0.f, 0.f};
    for (int kb = 0; kb < kpad; kb += 32) {
        h8 a = *(const h8*)(ap + kb);
        #pragma unroll
        for (int nt = 0; nt < NT; nt++) {
            h8 b = *(const h8*)(B + (long)(nt * 16 + (l & 15)) * kpad + kb + kg);
            acc[nt] = __builtin_amdgcn_mfma_f32_16x16x32_f16(a, b, acc[nt], 0, 0, 0);
        }
    }
    long rowo = m0 + (l >> 4) * 4;
    #pragma unroll
    for (int nt = 0; nt < NT; nt++) {
        int col = nt * 16 + (l & 15);
        if (col < ostride) {
            _Float16 vals[4];
            if (col < DIM) {
                float g = bn[col], be = bn[DIM + col], m = bn[2 * DIM + col],
                      v = bn[3 * DIM + col], bb = bias[col];
                float sc = g * rsqrtf(v + EPSB);
                #pragma unroll
                for (int rr = 0; rr < 4; rr++)
                    vals[rr] = (_Float16)tanhf(sc * (acc[nt][rr] + bb - m) + be);
            } else {
                #pragma unroll
                for (int rr = 0; rr < 4; rr++) vals[rr] = (_Float16)0.f;
            }
            #pragma unroll
            for (int rr = 0; rr < 4; rr++)
                C[(rowo + rr) * ostride + col] = vals[rr];
        }
    }
}

// =========== FUSED conv1d+bn1+relu + FC GEMM (split-K, atomics) ==============
__global__ __launch_bounds__(256) void k_convfc(
        const _Float16* __restrict__ hq16, const float* __restrict__ convw,
        const float* __restrict__ convb, const float* __restrict__ bn1,
        const _Float16* __restrict__ B, float* __restrict__ fcsum) {
    __shared__ _Float16 ldsA[64][40];
    __shared__ _Float16 ldsB[208][40];
    __shared__ float cwl[4][12];
    int bid = blockIdx.y * 8 + blockIdx.x;
    int wsw = (bid & 7) * 128 + (bid >> 3);
    int mb = wsw & 31, split = wsw >> 5;
    int t = threadIdx.x;
    int w = t >> 6, l = t & 63;
    int kbase = split * 800;
    int c0 = split * 4;
    if (t < 40) cwl[t / 10][t % 10] = convw[(c0 + t / 10) * 10 + t % 10];
    if (t < 4) {
        int c = c0 + t;
        float g = bn1[c], be = bn1[CCH + c], m = bn1[2 * CCH + c], v = bn1[3 * CCH + c];
        float s = g * rsqrtf(v + EPSB);
        cwl[t][10] = s;
        cwl[t][11] = be - m * s + s * convb[c];
    }
    __syncthreads();

    int r = t >> 2, q = t & 3;
    const _Float16* hrow = hq16 + (long)(mb * 64 + r) * 400;

    h8 z = {};
    h8 v0a, v1a, v2a, v0b, v1b, v2b;
    {
        int p = q * 8;
        v0a = (p >= 8) ? *(const h8*)(hrow + p - 8) : z;
        v1a = *(const h8*)(hrow + p);
        v2a = (p + 8 < DIM) ? *(const h8*)(hrow + p + 8) : z;
        v0b = (p >= 8) ? *(const h8*)(hrow + DIM + p - 8) : z;
        v1b = *(const h8*)(hrow + DIM + p);
        v2b = (p + 8 < DIM) ? *(const h8*)(hrow + DIM + p + 8) : z;
    }
    h8 bR[4];
    #pragma unroll
    for (int i2 = 0; i2 < 4; i2++) {
        int u = i2 * 256 + t;
        bR[i2] = (u < 832) ? *(const h8*)(B + (long)(u >> 2) * FCK + kbase + (u & 3) * 8) : z;
    }

    f32x4 acc[13];
    #pragma unroll
    for (int i = 0; i < 13; i++) acc[i] = (f32x4){0.f, 0.f, 0.f, 0.f};

    for (int ks = 0; ks < 25; ks++) {
        int off = ks * 32 + q * 8;
        int cl = off / 200;
        float cwv[12];
        #pragma unroll
        for (int k2 = 0; k2 < 12; k2++) cwv[k2] = cwl[cl][k2];
        float wa[12], wb[12];
        wa[0] = (float)v0a[6]; wa[1] = (float)v0a[7];
        wb[0] = (float)v0b[6]; wb[1] = (float)v0b[7];
        #pragma unroll
        for (int m2 = 0; m2 < 8; m2++) {
            wa[2 + m2] = (float)v1a[m2];
            wb[2 + m2] = (float)v1b[m2];
        }
        wa[10] = (float)v2a[0]; wa[11] = (float)v2a[1];
        wb[10] = (float)v2b[0]; wb[11] = (float)v2b[1];
        h8 aOut;
        #pragma unroll
        for (int j = 0; j < 8; j++) {
            float s = 0.f;
            #pragma unroll
            for (int kk = 0; kk < 5; kk++)
                s += wa[j + kk] * cwv[kk] + wb[j + kk] * cwv[5 + kk];
            aOut[j] = (_Float16)fmaxf(cwv[10] * s + cwv[11], 0.f);
        }
        *(h8*)&ldsA[r][q * 8] = aOut;
        #pragma unroll
        for (int i2 = 0; i2 < 4; i2++) {
            int u = i2 * 256 + t;
            if (u < 832) *(h8*)&ldsB[u >> 2][(u & 3) * 8] = bR[i2];
        }
        __syncthreads();
        if (ks + 1 < 25) {
            int off1 = (ks + 1) * 32 + q * 8;
            int cl1 = off1 / 200;
            int p1 = off1 - cl1 * 200;
            v0a = (p1 >= 8) ? *(const h8*)(hrow + p1 - 8) : z;
            v1a = *(const h8*)(hrow + p1);
            v2a = (p1 + 8 < DIM) ? *(const h8*)(hrow + p1 + 8) : z;
            v0b = (p1 >= 8) ? *(const h8*)(hrow + DIM + p1 - 8) : z;
            v1b = *(const h8*)(hrow + DIM + p1);
            v2b = (p1 + 8 < DIM) ? *(const h8*)(hrow + DIM + p1 + 8) : z;
            int knext = kbase + (ks + 1) * 32;
            #pragma unroll
            for (int i2 = 0; i2 < 4; i2++) {
                int u = i2 * 256 + t;
                if (u < 832) bR[i2] = *(const h8*)(B + (long)(u >> 2) * FCK + knext + (u & 3) * 8);
            }
        }
        h8 a = *(const h8*)&ldsA[w * 16 + (l & 15)][(l >> 4) * 8];
        #pragma unroll
        for (int nt = 0; nt < 13; nt++) {
            h8 b = *(const h8*)&ldsB[nt * 16 + (l & 15)][(l >> 4) * 8];
            acc[nt] = __builtin_amdgcn_mfma_f32_16x16x32_f16(a, b, acc[nt], 0, 0, 0);
        }
        __syncthreads();
    }
    long rowo = mb * 64 + w * 16 + (l >> 4) * 4;
    #pragma unroll
    for (int nt = 0; nt < 13; nt++) {
        int col = nt * 16 + (l & 15);
        if (col < DIM) {
            #pragma unroll
            for (int rr = 0; rr < 4; rr++)
                unsafeAtomicAdd(&fcsum[(rowo + rr) * DIM + col], acc[nt][rr]);
        }
    }
}

// =================== fcsum + bias + bn2 + relu -> h3 fp16 plane ===============
__global__ void k_fcreduce(const float* __restrict__ fcsum, const float* __restrict__ fcb,
                           const float* __restrict__ bn2, _Float16* __restrict__ h3) {
    int i = blockIdx.x * 256 + threadIdx.x;
    if (i >= BQ * KPAD) return;
    int j = i % KPAD, b = i / KPAD;
    _Float16 o = (_Float16)0.f;
    if (j < DIM) {
        float s = fcsum[(long)b * DIM + j] + fcb[j];
        float g = bn2[j], be = bn2[DIM + j], m = bn2[2 * DIM + j], v = bn2[3 * DIM + j];
        s = g * (s - m) * rsqrtf(v + EPSB) + be;
        o = (_Float16)fmaxf(s, 0.f);
    }
    h3[i] = o;
}

// =================== final: sigmoid(h3 @ e_all^T), fp16 MFMA =================
// grid (8, 625), XCD swizzle; wave = 64 rows x 64 cols (R15 proven shape);
// A+B reg double-buffer; LDS-transpose epilogue, full-line f32x4 NT stores.
__global__ __launch_bounds__(256) void k_mfma_final(
        const _Float16* __restrict__ A, const _Float16* __restrict__ B,
        float* __restrict__ out) {
    __shared__ float tl[4][32][68];
    int bid = blockIdx.y * 8 + blockIdx.x;
    int wsw = (bid & 7) * 625 + (bid >> 3);
    int mbb = wsw & 7, nbb = wsw >> 3;
    int w = threadIdx.x >> 6, l = threadIdx.x & 63;
    int n0 = nbb * 64;
    int m0 = mbb * 256 + w * 64;
    int lr = l & 15;
    int kb = (l >> 4) * 8;
    const _Float16* aph = A + (long)(m0 + lr) * KPAD + kb;
    const _Float16* bph = B + (long)(n0 + lr) * KPAD + kb;
    h8 ac[4], bc[4], an[4], bn_[4];
    #pragma unroll
    for (int x = 0; x < 4; x++) {
        ac[x] = *(const h8*)(aph + (long)x * 16 * KPAD);
        bc[x] = *(const h8*)(bph + (long)x * 16 * KPAD);
    }
    f32x4 acc[4][4];
    #pragma unroll
    for (int i = 0; i < 4; i++)
        #pragma unroll
        for (int j = 0; j < 4; j++) acc[i][j] = (f32x4){0.f, 0.f, 0.f, 0.f};
    for (int kt = 0; kt < 7; kt++) {
        int ko = kt * 32 + 32;
        if (kt < 6) {
            #pragma unroll
            for (int x = 0; x < 4; x++) {
                an[x]  = *(const h8*)(aph + (long)x * 16 * KPAD + ko);
                bn_[x] = *(const h8*)(bph + (long)x * 16 * KPAD + ko);
            }
        }
        #pragma unroll
        for (int mt = 0; mt < 4; mt++)
            #pragma unroll
            for (int nt = 0; nt < 4; nt++)
                acc[mt][nt] = __builtin_amdgcn_mfma_f32_16x16x32_f16(ac[mt], bc[nt], acc[mt][nt], 0, 0, 0);
        if (kt < 6) {
            #pragma unroll
            for (int x = 0; x < 4; x++) { ac[x] = an[x]; bc[x] = bn_[x]; }
        }
    }
    #pragma unroll
    for (int hh = 0; hh < 2; hh++) {
        #pragma unroll
        for (int mt2 = 0; mt2 < 2; mt2++) {
            int mt = hh * 2 + mt2;
            #pragma unroll
            for (int nt = 0; nt < 4; nt++)
                #pragma unroll
                for (int r = 0; r < 4; r++)
                    tl[w][mt2 * 16 + (l >> 4) * 4 + r][nt * 16 + lr] = acc[mt][nt][r];
        }
        // wave-local LDS reuse: in-wave lgkmcnt ordering suffices (no barrier)
        #pragma unroll
        for (int i = 0; i < 8; i++) {
            int rr = i * 4 + (l >> 4);
            f32x4 v = *(const f32x4*)&tl[w][rr][lr * 4];
            f32x4 o;
            o.x = __builtin_amdgcn_rcpf(1.f + __expf(-v.x));
            o.y = __builtin_amdgcn_rcpf(1.f + __expf(-v.y));
            o.z = __builtin_amdgcn_rcpf(1.f + __expf(-v.z));
            o.w = __builtin_amdgcn_rcpf(1.f + __expf(-v.w));
            long row = m0 + hh * 32 + rr;
            __builtin_nontemporal_store(o, (f32x4*)&out[row * NENT + n0 + lr * 4]);
        }
    }
}

extern "C" void kernel_launch(void* const* d_in, const int* in_sizes, int n_in,
                              void* d_out, int out_size, void* d_ws, size_t ws_size,
                              hipStream_t stream) {
    (void)in_sizes; (void)n_in; (void)out_size; (void)ws_size;
    const int* src      = (const int*)d_in[0];
    const int* dst      = (const int*)d_in[1];
    const int* aet      = (const int*)d_in[2];
    const int* e1       = (const int*)d_in[3];
    const int* rel      = (const int*)d_in[4];
    const int* entity   = (const int*)d_in[5];
    const float* emb_e  = (const float*)d_in[6];
    const float* embrel = (const float*)d_in[7];
    const float* w2     = (const float*)d_in[8];
    const float* b2     = (const float*)d_in[9];
    const float* alpha2 = (const float*)d_in[10];
    const float* w3     = (const float*)d_in[11];
    const float* b3     = (const float*)d_in[12];
    const float* alpha3 = (const float*)d_in[13];
    const float* bn3    = (const float*)d_in[14];
    const float* bn4    = (const float*)d_in[15];
    const float* bn0    = (const float*)d_in[16];
    const float* bn1    = (const float*)d_in[17];
    const float* bn2    = (const float*)d_in[18];
    const float* convw  = (const float*)d_in[19];
    const float* convb  = (const float*)d_in[20];
    const float* fcw    = (const float*)d_in[21];
    const float* fcb    = (const float*)d_in[22];
    float* out = (float*)d_out;
    float* ws = (float*)d_ws;

    // ---- workspace layout (float offsets; non-overlapping) ----
    _Float16* emb16 = (_Float16*)ws;                 // [40000][104]
    _Float16* aggE  = (_Float16*)(ws + 3000000);     // [40000][128]
    _Float16* x1_f  = (_Float16*)(ws + 6000000);     // [40000][200]
    _Float16* aggX  = (_Float16*)(ws + 11000000);    // [40000][224]
    _Float16* e_f   = (_Float16*)(ws + 16000000);    // [40000][224]
    _Float16* fcw_f = (_Float16*)(ws + 21000000);    // [208][25600]
    _Float16* hq16  = (_Float16*)(ws + 24000000);    // [2048][400]
    int*   deg    = (int*)(ws + 51000000);
    int*   rowptr = (int*)(ws + 51050000);
    int*   cursor = (int*)(ws + 51100000);
    int*   ssrc   = (int*)(ws + 51200000);
    float* sa1    = ws + 51800000;
    float* sa2    = ws + 52400000;
    float* fcsum  = ws + 53000000;
    _Float16* h3_f  = (_Float16*)(ws + 54400000);    // [2048][224]
    _Float16* w2t_f = (_Float16*)(ws + 54700000);    // [208][128]
    _Float16* w3t_f = (_Float16*)(ws + 54750000);    // [224][224]

    // ---- prep: zero deg/fcsum + all packs (one launch) ----
    k_prep<<<dim3(2600, 6), 256, 0, stream>>>(emb_e, entity, w2, w3, fcw,
                                              deg, fcsum, emb16, w2t_f, w3t_f, fcw_f);

    // ---- CSR build (shared by both layers) ----
    k_hist<<<(NE + 255) / 256, 256, 0, stream>>>(dst, deg);
    k_scan<<<1, 1024, 0, stream>>>(deg, rowptr, cursor);
    k_scatter<<<(NE + 255) / 256, 256, 0, stream>>>(src, dst, aet, alpha2, alpha3,
                                                    cursor, ssrc, sa1, sa2);

    // ---- GCN layer 1: aggregate RAW emb (linearity), then GEMM+bn3+tanh ----
    k_agg_raw<26, 32, EMBS, 128><<<NENT / 4, 256, 0, stream>>>(rowptr, ssrc, sa1,
                                                               emb16, aggE);
    k_gemm16f<13><<<NENT / 64, 256, 0, stream>>>(aggE, w2t_f, b2, bn3, x1_f, 128, DIM);

    // ---- GCN layer 2: aggregate x1, then GEMM+bn4+tanh -> e plane ----
    k_agg_raw<50, 56, DIM, KPAD><<<NENT / 4, 256, 0, stream>>>(rowptr, ssrc, sa2,
                                                               x1_f, aggX);
    k_gemm16f<14><<<NENT / 64, 256, 0, stream>>>(aggX, w3t_f, b3, bn4, e_f, KPAD, KPAD);

    // ---- decoder input ----
    k_hq16<<<(BQ * 2 * DIM + 255) / 256, 256, 0, stream>>>(e1, rel, e_f, embrel, bn0, hq16);

    // ---- fused conv + FC (no hconv materialization) ----
    k_convfc<<<dim3(8, 128), 256, 0, stream>>>(hq16, convw, convb, bn1, fcw_f, fcsum);
    k_fcreduce<<<(BQ * KPAD + 255) / 256, 256, 0, stream>>>(fcsum, fcb, bn2, h3_f);

    // ---- final scoring ----
    k_mfma_final<<<dim3(8, 625), 256, 0, stream>>>(h3_f, e_f, out);
}

// Round 18
// 502.225 us; speedup vs baseline: 1.0672x; 1.0056x over previous
//
#include <hip/hip_runtime.h>
#include <math.h>

#define NENT 40000
#define NTE  250000
#define NE   540000      // 2*NTE + NENT
#define DIM0 100
#define DIM  200
#define CCH  128
#define BQ   2048
#define FCK  25600       // CCH*DIM
#define EPSB 1e-5f
#define KPAD 224         // 200 padded to 7*32
#define EMBS 104         // emb16 row stride

typedef float f32x4 __attribute__((ext_vector_type(4)));
typedef _Float16 h8 __attribute__((ext_vector_type(8)));
typedef _Float16 h4 __attribute__((ext_vector_type(4)));

// =================== prep: zeroing + all input packing (one launch) ==========
// grid (2600, 6); section = blockIdx.y.
__global__ __launch_bounds__(256) void k_prep(
        const float* __restrict__ emb, const int* __restrict__ ent,
        const float* __restrict__ w2, const float* __restrict__ w3,
        const float* __restrict__ fcw,
        int* __restrict__ deg, float* __restrict__ fcsum,
        _Float16* __restrict__ emb16, _Float16* __restrict__ w2t,
        _Float16* __restrict__ w3t, _Float16* __restrict__ fcwf) {
    long i = (long)blockIdx.x * 256 + threadIdx.x;
    int sec = blockIdx.y;
    if (sec == 0) {
        if (i < NENT) deg[i] = 0;
    } else if (sec == 1) {
        if (i < BQ * DIM) fcsum[i] = 0.f;
    } else if (sec == 2) {
        if (i < (long)NENT * 13) {
            long m = i / 13;
            int k0 = (int)(i % 13) * 8;
            h8 h = {};
            const float* p = emb + (long)ent[m] * DIM0 + k0;
            #pragma unroll
            for (int j = 0; j < 8; j++)
                if (k0 + j < DIM0) h[j] = (_Float16)p[j];
            *(h8*)(emb16 + m * EMBS + k0) = h;
        }
    } else if (sec == 3) {
        if (i < 208 * 128) {
            int k = (int)(i % 128), n = (int)(i / 128);
            w2t[i] = (k < DIM0 && n < DIM) ? (_Float16)w2[(long)k * DIM + n] : (_Float16)0.f;
        }
    } else if (sec == 4) {
        if (i < 224 * KPAD) {
            int k = (int)(i % KPAD), n = (int)(i / KPAD);
            w3t[i] = (k < DIM && n < DIM) ? (_Float16)w3[(long)k * DIM + n] : (_Float16)0.f;
        }
    } else {
        if (i < (long)208 * (FCK / 8)) {
            int n = (int)(i / (FCK / 8));
            long k0 = (i % (FCK / 8)) * 8;
            h8 h = {};
            if (n < DIM) {
                const float* p = fcw + (long)n * FCK + k0;
                #pragma unroll
                for (int j = 0; j < 8; j++) h[j] = (_Float16)p[j];
            }
            *(h8*)(fcwf + (long)n * FCK + k0) = h;
        }
    }
}

// =================== CSR build ===================
__global__ void k_hist(const int* __restrict__ dst, int* __restrict__ deg) {
    int e = blockIdx.x * 256 + threadIdx.x;
    if (e < NE) atomicAdd(&deg[dst[e]], 1);
}

__global__ __launch_bounds__(1024) void k_scan(const int* __restrict__ deg,
        int* __restrict__ rowptr, int* __restrict__ cursor) {
    __shared__ int sums[1024];
    int t = threadIdx.x;
    int base = t * 40;
    int local[40];
    int s = 0;
    #pragma unroll
    for (int i = 0; i < 40; i++) {
        int idx = base + i;
        int v = (idx < NENT) ? deg[idx] : 0;
        local[i] = s;
        s += v;
    }
    sums[t] = s;
    __syncthreads();
    #pragma unroll
    for (int off = 1; off < 1024; off <<= 1) {
        int add = (t >= off) ? sums[t - off] : 0;
        __syncthreads();
        sums[t] += add;
        __syncthreads();
    }
    int prefix = (t == 0) ? 0 : sums[t - 1];
    #pragma unroll
    for (int i = 0; i < 40; i++) {
        int idx = base + i;
        if (idx < NENT) {
            int p = prefix + local[i];
            rowptr[idx] = p;
            cursor[idx] = p;
        }
    }
    if (t == 1023) rowptr[NENT] = prefix + s;
}

__global__ void k_scatter(const int* __restrict__ src, const int* __restrict__ dst,
                          const int* __restrict__ aet, const float* __restrict__ a2t,
                          const float* __restrict__ a3t, int* __restrict__ cursor,
                          int* __restrict__ ssrc, float* __restrict__ sa1,
                          float* __restrict__ sa2) {
    int e = blockIdx.x * 256 + threadIdx.x;
    if (e >= NE) return;
    int tt = (e < NTE) ? e + NTE : (e < 2 * NTE ? e - NTE : e);
    int t0 = aet[e], t1 = aet[tt];
    int pos = atomicAdd(&cursor[dst[e]], 1);
    ssrc[pos] = src[e];
    sa1[pos] = a2t[t0] + a2t[t1];
    sa2[pos] = a3t[t0] + a3t[t1];
}

// =================== raw CSR aggregation (pre-GEMM, linearity) ===============
// One wave per dst row; 8-edge unroll (8 independent gathers in flight halves
// the serial latency-chain steps vs 4). fp32 accum, fp16 in/out.
template<int NL, int NPADL, int SS, int OS>
__global__ __launch_bounds__(256) void k_agg_raw(const int* __restrict__ rowptr,
        const int* __restrict__ ssrc, const float* __restrict__ sa,
        const _Float16* __restrict__ srcd, _Float16* __restrict__ outd) {
    int w = threadIdx.x >> 6, l = threadIdx.x & 63;
    int row = blockIdx.x * 4 + w;
    int beg = rowptr[row], end = rowptr[row + 1];
    bool act = l < NL;
    int col = l * 4;
    float sx = 0.f, sy = 0.f, sz = 0.f, sw = 0.f;
    int i = beg;
    for (; i + 8 <= end; i += 8) {
        int idx[8];
        float av[8];
        #pragma unroll
        for (int j = 0; j < 8; j++) { idx[j] = ssrc[i + j]; av[j] = sa[i + j]; }
        if (act) {
            h4 v[8];
            #pragma unroll
            for (int j = 0; j < 8; j++)
                v[j] = *(const h4*)(srcd + (long)idx[j] * SS + col);
            #pragma unroll
            for (int j = 0; j < 8; j++) {
                sx += av[j] * (float)v[j][0];
                sy += av[j] * (float)v[j][1];
                sz += av[j] * (float)v[j][2];
                sw += av[j] * (float)v[j][3];
            }
        }
    }
    if (i + 4 <= end) {
        int i0 = ssrc[i], i1 = ssrc[i + 1], i2 = ssrc[i + 2], i3 = ssrc[i + 3];
        float a0 = sa[i], a1 = sa[i + 1], a2 = sa[i + 2], a3 = sa[i + 3];
        if (act) {
            h4 v0 = *(const h4*)(srcd + (long)i0 * SS + col);
            h4 v1 = *(const h4*)(srcd + (long)i1 * SS + col);
            h4 v2 = *(const h4*)(srcd + (long)i2 * SS + col);
            h4 v3 = *(const h4*)(srcd + (long)i3 * SS + col);
            sx += a0 * (float)v0[0] + a1 * (float)v1[0] + a2 * (float)v2[0] + a3 * (float)v3[0];
            sy += a0 * (float)v0[1] + a1 * (float)v1[1] + a2 * (float)v2[1] + a3 * (float)v3[1];
            sz += a0 * (float)v0[2] + a1 * (float)v1[2] + a2 * (float)v2[2] + a3 * (float)v3[2];
            sw += a0 * (float)v0[3] + a1 * (float)v1[3] + a2 * (float)v2[3] + a3 * (float)v3[3];
        }
        i += 4;
    }
    for (; i < end; i++) {
        int i0 = ssrc[i];
        float a0 = sa[i];
        if (act) {
            h4 v0 = *(const h4*)(srcd + (long)i0 * SS + col);
            sx += a0 * (float)v0[0]; sy += a0 * (float)v0[1];
            sz += a0 * (float)v0[2]; sw += a0 * (float)v0[3];
        }
    }
    if (act) {
        h4 o = { (_Float16)sx, (_Float16)sy, (_Float16)sz, (_Float16)sw };
        *(h4*)(outd + (long)row * OS + col) = o;
    } else if (l < NPADL) {
        h4 z = { (_Float16)0.f, (_Float16)0.f, (_Float16)0.f, (_Float16)0.f };
        *(h4*)(outd + (long)row * OS + col) = z;
    }
}

// decoder input: bn0-normalized [e(fp16 plane); rel_emb] -> hq16 fp16 [2048][400]
__global__ void k_hq16(const int* __restrict__ e1, const int* __restrict__ rel,
                       const _Float16* __restrict__ ef, const float* __restrict__ embrel,
                       const float* __restrict__ bn0, _Float16* __restrict__ hq) {
    int i = blockIdx.x * 256 + threadIdx.x;
    if (i >= BQ * 2 * DIM) return;
    int d = i % DIM, c = (i / DIM) & 1, b = i / (2 * DIM);
    float val = (c == 0) ? (float)ef[(long)e1[b] * KPAD + d]
                         : embrel[(long)rel[b] * DIM + d];
    float g = bn0[c], be = bn0[2 + c], m = bn0[4 + c], v = bn0[6 + c];
    hq[i] = (_Float16)(g * (val - m) * rsqrtf(v + EPSB) + be);
}

// ======= layer GEMM fused epilogue: C = tanh(bn(A@B + bias)) -> fp16 =========
template<int NT>
__global__ __launch_bounds__(256) void k_gemm16f(
        const _Float16* __restrict__ A, const _Float16* __restrict__ B,
        const float* __restrict__ bias, const float* __restrict__ bn,
        _Float16* __restrict__ C, int kpad, int ostride) {
    int w = threadIdx.x >> 6, l = threadIdx.x & 63;
    long m0 = (long)blockIdx.x * 64 + w * 16;
    long arow = m0 + (l & 15);
    int kg = (l >> 4) * 8;
    const _Float16* ap = A + arow * kpad + kg;
    f32x4 acc[NT];
    #pragma unroll
    for (int i = 0; i < NT; i++) acc[i] = (f32x4){0.f, 0.f, 0.f, 0.f};
    for (int kb = 0; kb < kpad; kb += 32) {
        h8 a = *(const h8*)(ap + kb);
        #pragma unroll
        for (int nt = 0; nt < NT; nt++) {
            h8 b = *(const h8*)(B + (long)(nt * 16 + (l & 15)) * kpad + kb + kg);
            acc[nt] = __builtin_amdgcn_mfma_f32_16x16x32_f16(a, b, acc[nt], 0, 0, 0);
        }
    }
    long rowo = m0 + (l >> 4) * 4;
    #pragma unroll
    for (int nt = 0; nt < NT; nt++) {
        int col = nt * 16 + (l & 15);
        if (col < ostride) {
            _Float16 vals[4];
            if (col < DIM) {
                float g = bn[col], be = bn[DIM + col], m = bn[2 * DIM + col],
                      v = bn[3 * DIM + col], bb = bias[col];
                float sc = g * rsqrtf(v + EPSB);
                #pragma unroll
                for (int rr = 0; rr < 4; rr++)
                    vals[rr] = (_Float16)tanhf(sc * (acc[nt][rr] + bb - m) + be);
            } else {
                #pragma unroll
                for (int rr = 0; rr < 4; rr++) vals[rr] = (_Float16)0.f;
            }
            #pragma unroll
            for (int rr = 0; rr < 4; rr++)
                C[(rowo + rr) * ostride + col] = vals[rr];
        }
    }
}

// =========== FUSED conv1d+bn1+relu + FC GEMM (split-K, atomics) ==============
__global__ __launch_bounds__(256) void k_convfc(
        const _Float16* __restrict__ hq16, const float* __restrict__ convw,
        const float* __restrict__ convb, const float* __restrict__ bn1,
        const _Float16* __restrict__ B, float* __restrict__ fcsum) {
    __shared__ _Float16 ldsA[64][40];
    __shared__ _Float16 ldsB[208][40];
    __shared__ float cwl[4][12];
    int bid = blockIdx.y * 8 + blockIdx.x;
    int wsw = (bid & 7) * 128 + (bid >> 3);
    int mb = wsw & 31, split = wsw >> 5;
    int t = threadIdx.x;
    int w = t >> 6, l = t & 63;
    int kbase = split * 800;
    int c0 = split * 4;
    if (t < 40) cwl[t / 10][t % 10] = convw[(c0 + t / 10) * 10 + t % 10];
    if (t < 4) {
        int c = c0 + t;
        float g = bn1[c], be = bn1[CCH + c], m = bn1[2 * CCH + c], v = bn1[3 * CCH + c];
        float s = g * rsqrtf(v + EPSB);
        cwl[t][10] = s;
        cwl[t][11] = be - m * s + s * convb[c];
    }
    __syncthreads();

    int r = t >> 2, q = t & 3;
    const _Float16* hrow = hq16 + (long)(mb * 64 + r) * 400;

    h8 z = {};
    h8 v0a, v1a, v2a, v0b, v1b, v2b;
    {
        int p = q * 8;
        v0a = (p >= 8) ? *(const h8*)(hrow + p - 8) : z;
        v1a = *(const h8*)(hrow + p);
        v2a = (p + 8 < DIM) ? *(const h8*)(hrow + p + 8) : z;
        v0b = (p >= 8) ? *(const h8*)(hrow + DIM + p - 8) : z;
        v1b = *(const h8*)(hrow + DIM + p);
        v2b = (p + 8 < DIM) ? *(const h8*)(hrow + DIM + p + 8) : z;
    }
    h8 bR[4];
    #pragma unroll
    for (int i2 = 0; i2 < 4; i2++) {
        int u = i2 * 256 + t;
        bR[i2] = (u < 832) ? *(const h8*)(B + (long)(u >> 2) * FCK + kbase + (u & 3) * 8) : z;
    }

    f32x4 acc[13];
    #pragma unroll
    for (int i = 0; i < 13; i++) acc[i] = (f32x4){0.f, 0.f, 0.f, 0.f};

    for (int ks = 0; ks < 25; ks++) {
        int off = ks * 32 + q * 8;
        int cl = off / 200;
        float cwv[12];
        #pragma unroll
        for (int k2 = 0; k2 < 12; k2++) cwv[k2] = cwl[cl][k2];
        float wa[12], wb[12];
        wa[0] = (float)v0a[6]; wa[1] = (float)v0a[7];
        wb[0] = (float)v0b[6]; wb[1] = (float)v0b[7];
        #pragma unroll
        for (int m2 = 0; m2 < 8; m2++) {
            wa[2 + m2] = (float)v1a[m2];
            wb[2 + m2] = (float)v1b[m2];
        }
        wa[10] = (float)v2a[0]; wa[11] = (float)v2a[1];
        wb[10] = (float)v2b[0]; wb[11] = (float)v2b[1];
        h8 aOut;
        #pragma unroll
        for (int j = 0; j < 8; j++) {
            float s = 0.f;
            #pragma unroll
            for (int kk = 0; kk < 5; kk++)
                s += wa[j + kk] * cwv[kk] + wb[j + kk] * cwv[5 + kk];
            aOut[j] = (_Float16)fmaxf(cwv[10] * s + cwv[11], 0.f);
        }
        *(h8*)&ldsA[r][q * 8] = aOut;
        #pragma unroll
        for (int i2 = 0; i2 < 4; i2++) {
            int u = i2 * 256 + t;
            if (u < 832) *(h8*)&ldsB[u >> 2][(u & 3) * 8] = bR[i2];
        }
        __syncthreads();
        if (ks + 1 < 25) {
            int off1 = (ks + 1) * 32 + q * 8;
            int cl1 = off1 / 200;
            int p1 = off1 - cl1 * 200;
            v0a = (p1 >= 8) ? *(const h8*)(hrow + p1 - 8) : z;
            v1a = *(const h8*)(hrow + p1);
            v2a = (p1 + 8 < DIM) ? *(const h8*)(hrow + p1 + 8) : z;
            v0b = (p1 >= 8) ? *(const h8*)(hrow + DIM + p1 - 8) : z;
            v1b = *(const h8*)(hrow + DIM + p1);
            v2b = (p1 + 8 < DIM) ? *(const h8*)(hrow + DIM + p1 + 8) : z;
            int knext = kbase + (ks + 1) * 32;
            #pragma unroll
            for (int i2 = 0; i2 < 4; i2++) {
                int u = i2 * 256 + t;
                if (u < 832) bR[i2] = *(const h8*)(B + (long)(u >> 2) * FCK + knext + (u & 3) * 8);
            }
        }
        h8 a = *(const h8*)&ldsA[w * 16 + (l & 15)][(l >> 4) * 8];
        #pragma unroll
        for (int nt = 0; nt < 13; nt++) {
            h8 b = *(const h8*)&ldsB[nt * 16 + (l & 15)][(l >> 4) * 8];
            acc[nt] = __builtin_amdgcn_mfma_f32_16x16x32_f16(a, b, acc[nt], 0, 0, 0);
        }
        __syncthreads();
    }
    long rowo = mb * 64 + w * 16 + (l >> 4) * 4;
    #pragma unroll
    for (int nt = 0; nt < 13; nt++) {
        int col = nt * 16 + (l & 15);
        if (col < DIM) {
            #pragma unroll
            for (int rr = 0; rr < 4; rr++)
                unsafeAtomicAdd(&fcsum[(rowo + rr) * DIM + col], acc[nt][rr]);
        }
    }
}

// =================== fcsum + bias + bn2 + relu -> h3 fp16 plane ===============
__global__ void k_fcreduce(const float* __restrict__ fcsum, const float* __restrict__ fcb,
                           const float* __restrict__ bn2, _Float16* __restrict__ h3) {
    int i = blockIdx.x * 256 + threadIdx.x;
    if (i >= BQ * KPAD) return;
    int j = i % KPAD, b = i / KPAD;
    _Float16 o = (_Float16)0.f;
    if (j < DIM) {
        float s = fcsum[(long)b * DIM + j] + fcb[j];
        float g = bn2[j], be = bn2[DIM + j], m = bn2[2 * DIM + j], v = bn2[3 * DIM + j];
        s = g * (s - m) * rsqrtf(v + EPSB) + be;
        o = (_Float16)fmaxf(s, 0.f);
    }
    h3[i] = o;
}

// =================== final: sigmoid(h3 @ e_all^T), fp16 MFMA =================
// grid (8, 625), XCD swizzle; wave = 64 rows x 64 cols; A+B reg double-buffer;
// LDS-transpose epilogue, full-line f32x4 NT stores.
__global__ __launch_bounds__(256) void k_mfma_final(
        const _Float16* __restrict__ A, const _Float16* __restrict__ B,
        float* __restrict__ out) {
    __shared__ float tl[4][32][68];
    int bid = blockIdx.y * 8 + blockIdx.x;
    int wsw = (bid & 7) * 625 + (bid >> 3);
    int mbb = wsw & 7, nbb = wsw >> 3;
    int w = threadIdx.x >> 6, l = threadIdx.x & 63;
    int n0 = nbb * 64;
    int m0 = mbb * 256 + w * 64;
    int lr = l & 15;
    int kb = (l >> 4) * 8;
    const _Float16* aph = A + (long)(m0 + lr) * KPAD + kb;
    const _Float16* bph = B + (long)(n0 + lr) * KPAD + kb;
    h8 ac[4], bc[4], an[4], bn_[4];
    #pragma unroll
    for (int x = 0; x < 4; x++) {
        ac[x] = *(const h8*)(aph + (long)x * 16 * KPAD);
        bc[x] = *(const h8*)(bph + (long)x * 16 * KPAD);
    }
    f32x4 acc[4][4];
    #pragma unroll
    for (int i = 0; i < 4; i++)
        #pragma unroll
        for (int j = 0; j < 4; j++) acc[i][j] = (f32x4){0.f, 0.f, 0.f, 0.f};
    for (int kt = 0; kt < 7; kt++) {
        int ko = kt * 32 + 32;
        if (kt < 6) {
            #pragma unroll
            for (int x = 0; x < 4; x++) {
                an[x]  = *(const h8*)(aph + (long)x * 16 * KPAD + ko);
                bn_[x] = *(const h8*)(bph + (long)x * 16 * KPAD + ko);
            }
        }
        #pragma unroll
        for (int mt = 0; mt < 4; mt++)
            #pragma unroll
            for (int nt = 0; nt < 4; nt++)
                acc[mt][nt] = __builtin_amdgcn_mfma_f32_16x16x32_f16(ac[mt], bc[nt], acc[mt][nt], 0, 0, 0);
        if (kt < 6) {
            #pragma unroll
            for (int x = 0; x < 4; x++) { ac[x] = an[x]; bc[x] = bn_[x]; }
        }
    }
    #pragma unroll
    for (int hh = 0; hh < 2; hh++) {
        #pragma unroll
        for (int mt2 = 0; mt2 < 2; mt2++) {
            int mt = hh * 2 + mt2;
            #pragma unroll
            for (int nt = 0; nt < 4; nt++)
                #pragma unroll
                for (int r = 0; r < 4; r++)
                    tl[w][mt2 * 16 + (l >> 4) * 4 + r][nt * 16 + lr] = acc[mt][nt][r];
        }
        // wave-local LDS reuse: in-wave lgkmcnt ordering suffices (no barrier)
        #pragma unroll
        for (int i = 0; i < 8; i++) {
            int rr = i * 4 + (l >> 4);
            f32x4 v = *(const f32x4*)&tl[w][rr][lr * 4];
            f32x4 o;
            o.x = __builtin_amdgcn_rcpf(1.f + __expf(-v.x));
            o.y = __builtin_amdgcn_rcpf(1.f + __expf(-v.y));
            o.z = __builtin_amdgcn_rcpf(1.f + __expf(-v.z));
            o.w = __builtin_amdgcn_rcpf(1.f + __expf(-v.w));
            long row = m0 + hh * 32 + rr;
            __builtin_nontemporal_store(o, (f32x4*)&out[row * NENT + n0 + lr * 4]);
        }
    }
}

extern "C" void kernel_launch(void* const* d_in, const int* in_sizes, int n_in,
                              void* d_out, int out_size, void* d_ws, size_t ws_size,
                              hipStream_t stream) {
    (void)in_sizes; (void)n_in; (void)out_size; (void)ws_size;
    const int* src      = (const int*)d_in[0];
    const int* dst      = (const int*)d_in[1];
    const int* aet      = (const int*)d_in[2];
    const int* e1       = (const int*)d_in[3];
    const int* rel      = (const int*)d_in[4];
    const int* entity   = (const int*)d_in[5];
    const float* emb_e  = (const float*)d_in[6];
    const float* embrel = (const float*)d_in[7];
    const float* w2     = (const float*)d_in[8];
    const float* b2     = (const float*)d_in[9];
    const float* alpha2 = (const float*)d_in[10];
    const float* w3     = (const float*)d_in[11];
    const float* b3     = (const float*)d_in[12];
    const float* alpha3 = (const float*)d_in[13];
    const float* bn3    = (const float*)d_in[14];
    const float* bn4    = (const float*)d_in[15];
    const float* bn0    = (const float*)d_in[16];
    const float* bn1    = (const float*)d_in[17];
    const float* bn2    = (const float*)d_in[18];
    const float* convw  = (const float*)d_in[19];
    const float* convb  = (const float*)d_in[20];
    const float* fcw    = (const float*)d_in[21];
    const float* fcb    = (const float*)d_in[22];
    float* out = (float*)d_out;
    float* ws = (float*)d_ws;

    // ---- workspace layout (float offsets; non-overlapping) ----
    _Float16* emb16 = (_Float16*)ws;                 // [40000][104]
    _Float16* aggE  = (_Float16*)(ws + 3000000);     // [40000][128]
    _Float16* x1_f  = (_Float16*)(ws + 6000000);     // [40000][200]
    _Float16* aggX  = (_Float16*)(ws + 11000000);    // [40000][224]
    _Float16* e_f   = (_Float16*)(ws + 16000000);    // [40000][224]
    _Float16* fcw_f = (_Float16*)(ws + 21000000);    // [208][25600]
    _Float16* hq16  = (_Float16*)(ws + 24000000);    // [2048][400]
    int*   deg    = (int*)(ws + 51000000);
    int*   rowptr = (int*)(ws + 51050000);
    int*   cursor = (int*)(ws + 51100000);
    int*   ssrc   = (int*)(ws + 51200000);
    float* sa1    = ws + 51800000;
    float* sa2    = ws + 52400000;
    float* fcsum  = ws + 53000000;
    _Float16* h3_f  = (_Float16*)(ws + 54400000);    // [2048][224]
    _Float16* w2t_f = (_Float16*)(ws + 54700000);    // [208][128]
    _Float16* w3t_f = (_Float16*)(ws + 54750000);    // [224][224]

    // ---- prep: zero deg/fcsum + all packs (one launch) ----
    k_prep<<<dim3(2600, 6), 256, 0, stream>>>(emb_e, entity, w2, w3, fcw,
                                              deg, fcsum, emb16, w2t_f, w3t_f, fcw_f);

    // ---- CSR build (shared by both layers) ----
    k_hist<<<(NE + 255) / 256, 256, 0, stream>>>(dst, deg);
    k_scan<<<1, 1024, 0, stream>>>(deg, rowptr, cursor);
    k_scatter<<<(NE + 255) / 256, 256, 0, stream>>>(src, dst, aet, alpha2, alpha3,
                                                    cursor, ssrc, sa1, sa2);

    // ---- GCN layer 1: aggregate RAW emb (linearity), then GEMM+bn3+tanh ----
    k_agg_raw<26, 32, EMBS, 128><<<NENT / 4, 256, 0, stream>>>(rowptr, ssrc, sa1,
                                                               emb16, aggE);
    k_gemm16f<13><<<NENT / 64, 256, 0, stream>>>(aggE, w2t_f, b2, bn3, x1_f, 128, DIM);

    // ---- GCN layer 2: aggregate x1, then GEMM+bn4+tanh -> e plane ----
    k_agg_raw<50, 56, DIM, KPAD><<<NENT / 4, 256, 0, stream>>>(rowptr, ssrc, sa2,
                                                               x1_f, aggX);
    k_gemm16f<14><<<NENT / 64, 256, 0, stream>>>(aggX, w3t_f, b3, bn4, e_f, KPAD, KPAD);

    // ---- decoder input ----
    k_hq16<<<(BQ * 2 * DIM + 255) / 256, 256, 0, stream>>>(e1, rel, e_f, embrel, bn0, hq16);

    // ---- fused conv + FC (no hconv materialization) ----
    k_convfc<<<dim3(8, 128), 256, 0, stream>>>(hq16, convw, convb, bn1, fcw_f, fcsum);
    k_fcreduce<<<(BQ * KPAD + 255) / 256, 256, 0, stream>>>(fcsum, fcb, bn2, h3_f);

    // ---- final scoring ----
    k_mfma_final<<<dim3(8, 625), 256, 0, stream>>>(h3_f, e_f, out);
}